// Round 1
// baseline (187.624 us; speedup 1.0000x reference)
//
#include <hip/hip_runtime.h>
#include <cstdint>
#include <cstddef>

// Problem constants
// B=32, S=2048, P=256, N=256, K=8, L=4, M_out=1024 (=L*P)
// out[b, t, n] = (sum_s A[t,s]*xn[b,s,n] + b_enc[t>>8]) * stdev[b,n] + mean[b,n]
// A[l*256+q, k*256+p] = W_enc[l,k] * (W^(8-k+l))[q,p]

typedef unsigned short ushort_t;
typedef unsigned int uint_t;
typedef __attribute__((ext_vector_type(8))) short bf16x8;
typedef __attribute__((ext_vector_type(16))) float f32x16;

__device__ __forceinline__ ushort_t f32_to_bf16(float f) {
    uint_t u = __float_as_uint(f);
    u += 0x7FFFu + ((u >> 16) & 1u);   // RNE (finite values only here)
    return (ushort_t)(u >> 16);
}
__device__ __forceinline__ float bf16_to_f32(ushort_t h) {
    return __uint_as_float((uint_t)h << 16);
}

// ---------------- stats: mean/std per (b,n) over s=0..2047 ----------------
__global__ void stats_partial(const float* __restrict__ x,
                              float* __restrict__ psum, float* __restrict__ psq) {
    const int c = blockIdx.x;   // chunk 0..15 (128 s each)
    const int b = blockIdx.y;   // 0..31
    const int n = threadIdx.x;  // 0..255
    float s = 0.f, q = 0.f;
    const float* xp = x + ((size_t)b * 2048 + (size_t)c * 128) * 256 + n;
#pragma unroll 4
    for (int i = 0; i < 128; ++i) { float v = xp[(size_t)i * 256]; s += v; q += v * v; }
    psum[(b * 16 + c) * 256 + n] = s;
    psq [(b * 16 + c) * 256 + n] = q;
}

__global__ void stats_final(const float* __restrict__ psum, const float* __restrict__ psq,
                            float* __restrict__ meanv, float* __restrict__ stdv,
                            float* __restrict__ rstdv) {
    const int b = blockIdx.x; const int n = threadIdx.x;
    float s = 0.f, q = 0.f;
#pragma unroll
    for (int c = 0; c < 16; ++c) { s += psum[(b * 16 + c) * 256 + n]; q += psq[(b * 16 + c) * 256 + n]; }
    const float mean = s * (1.0f / 2048.0f);
    float var = q * (1.0f / 2048.0f) - mean * mean;
    var = fmaxf(var, 0.0f);
    const float sd = sqrtf(var + 1e-5f);
    meanv[b * 256 + n] = mean;
    stdv [b * 256 + n] = sd;
    rstdv[b * 256 + n] = 1.0f / sd;
}

// ---------------- W powers: C = A * B for up to 4 (slot) triples ----------------
struct PowOps { int sa[4]; int sb[4]; int sd[4]; };

__global__ void powmul(float* __restrict__ Pw, PowOps ops) {
    __shared__ float As[4 * 256];
    const int mat = blockIdx.x;
    const int r0  = blockIdx.y * 4;      // 64 row-blocks of 4
    const int tid = threadIdx.x;         // 256
    const float* A  = Pw + (size_t)ops.sa[mat] * 65536;
    const float* Bm = Pw + (size_t)ops.sb[mat] * 65536;
    float* C        = Pw + (size_t)ops.sd[mat] * 65536;
#pragma unroll
    for (int i = 0; i < 4; ++i) As[i * 256 + tid] = A[(r0 + i) * 256 + tid];
    __syncthreads();
    float a0 = 0.f, a1 = 0.f, a2 = 0.f, a3 = 0.f;
    for (int p = 0; p < 256; ++p) {
        const float bv = Bm[p * 256 + tid];
        a0 += As[0 * 256 + p] * bv;
        a1 += As[1 * 256 + p] * bv;
        a2 += As[2 * 256 + p] * bv;
        a3 += As[3 * 256 + p] * bv;
    }
    C[(r0 + 0) * 256 + tid] = a0;
    C[(r0 + 1) * 256 + tid] = a1;
    C[(r0 + 2) * 256 + tid] = a2;
    C[(r0 + 3) * 256 + tid] = a3;
}

// ---------------- build A (scaled by W_enc), split into bf16 hi/lo ----------------
__global__ void buildA(const float* __restrict__ Pw, const float* __restrict__ Wenc,
                       ushort_t* __restrict__ Ah, ushort_t* __restrict__ Al) {
    const int t = blockIdx.y;                      // 0..1023
    const int s = blockIdx.x * 256 + threadIdx.x;  // 0..2047
    const int l = t >> 8, q = t & 255, k = s >> 8, p = s & 255;
    const int m = 8 - k + l;                       // 1..11
    const float val = Wenc[l * 8 + k] * Pw[(size_t)(m - 1) * 65536 + q * 256 + p];
    const ushort_t hi = f32_to_bf16(val);
    const float hif = bf16_to_f32(hi);
    const ushort_t lo = f32_to_bf16(val - hif);
    Ah[(size_t)t * 2048 + s] = hi;
    Al[(size_t)t * 2048 + s] = lo;
}

// ---------------- normalize + split + transpose: Xt[b][n][s] bf16 hi/lo ----------------
__global__ void normsplit(const float* __restrict__ x, const float* __restrict__ meanv,
                          const float* __restrict__ rstdv,
                          ushort_t* __restrict__ Xh, ushort_t* __restrict__ Xl) {
    __shared__ uint_t lds[64 * 65];                // packed (hi<<16)|lo, padded stride
    const int st = blockIdx.x;                     // s-tile 0..31
    const int nt = blockIdx.y;                     // n-tile 0..3
    const int b  = blockIdx.z;                     // 0..31
    const int tid = threadIdx.x;
    const int j = tid & 63;
    const int n = nt * 64 + j;
    const float mn = meanv[b * 256 + n];
    const float rs = rstdv[b * 256 + n];
    const int s0 = st * 64;
#pragma unroll
    for (int it = 0; it < 16; ++it) {
        const int ii = (tid >> 6) + it * 4;
        const float v = x[((size_t)b * 2048 + s0 + ii) * 256 + n];
        const float xn = (v - mn) * rs;
        const ushort_t hi = f32_to_bf16(xn);
        const float hif = bf16_to_f32(hi);
        const ushort_t lo = f32_to_bf16(xn - hif);
        lds[ii * 65 + j] = ((uint_t)hi << 16) | (uint_t)lo;
    }
    __syncthreads();
#pragma unroll
    for (int step = 0; step < 8; ++step) {
        const int npr = step * 8 + (tid >> 5);     // 0..63 (n within tile)
        const int sp  = (tid & 31) * 2;            // even s within tile
        const uint_t w0 = lds[sp * 65 + npr];
        const uint_t w1 = lds[(sp + 1) * 65 + npr];
        const size_t base = ((size_t)b * 256 + nt * 64 + npr) * 2048 + s0 + sp;
        *(uint_t*)(Xh + base) = (w0 >> 16) | (w1 & 0xFFFF0000u);
        *(uint_t*)(Xl + base) = (w0 & 0xFFFFu) | (w1 << 16);
    }
}

// ---------------- GEMM: out[b,t,n] = (A @ Xt[b]^T)[t,n] epilogue-fused ----------------
// A: [1024][2048] bf16 hi/lo (row-major). Xt: [b][256][2048] bf16 hi/lo.
// Tile 128x128, BK=64, 4 waves (2x2), 32x32x16 bf16 MFMA, 3-product split emulation.
#define GLOAD_LDS16(gsrc, ldst) \
    __builtin_amdgcn_global_load_lds((const __attribute__((address_space(1))) void*)(gsrc), \
                                     (__attribute__((address_space(3))) void*)(ldst), 16, 0, 0)

__global__ __launch_bounds__(256, 2) void gemm_kernel(
    const ushort_t* __restrict__ Ah, const ushort_t* __restrict__ Al,
    const ushort_t* __restrict__ Xh, const ushort_t* __restrict__ Xl,
    const float* __restrict__ meanv, const float* __restrict__ stdv,
    const float* __restrict__ benc, float* __restrict__ out)
{
    __shared__ ushort_t sAh[128 * 64];
    __shared__ ushort_t sAl[128 * 64];
    __shared__ ushort_t sXh[128 * 64];
    __shared__ ushort_t sXl[128 * 64];

    const int by = blockIdx.x;     // M tile: rows by*128  (0..7)
    const int bx = blockIdx.y;     // N tile: cols bx*128  (0..1)
    const int b  = blockIdx.z;     // batch 0..31
    const int tid  = threadIdx.x;
    const int lane = tid & 63;
    const int w    = tid >> 6;     // wave 0..3
    const int wr   = w >> 1, wc = w & 1;

    const ushort_t* Xhb = Xh + (size_t)b * (256 * 2048);
    const ushort_t* Xlb = Xl + (size_t)b * (256 * 2048);

    const int srow   = lane >> 3;  // 0..7 row-within-8 for staging
    const int schunk = lane & 7;   // 16B chunk within 128B row

    f32x16 acc[2][2];
#pragma unroll
    for (int m = 0; m < 2; ++m)
#pragma unroll
        for (int n = 0; n < 2; ++n)
#pragma unroll
            for (int r = 0; r < 16; ++r) acc[m][n][r] = 0.0f;

    for (int kt = 0; kt < 32; ++kt) {
        const int k0 = kt * 64;
        __syncthreads();
#pragma unroll
        for (int i = 0; i < 4; ++i) {
            const int r  = i * 32 + w * 8 + srow;          // LDS row 0..127
            const int ch = schunk ^ (r & 7);               // pre-swizzled source chunk
            const size_t ga = (size_t)(by * 128 + r) * 2048 + k0 + ch * 8;
            const size_t gx = (size_t)(bx * 128 + r) * 2048 + k0 + ch * 8;
            const uint_t ldsoff = (uint_t)(i * 32 + w * 8) * 64;  // elements
            GLOAD_LDS16(Ah + ga,  sAh + ldsoff);
            GLOAD_LDS16(Al + ga,  sAl + ldsoff);
            GLOAD_LDS16(Xhb + gx, sXh + ldsoff);
            GLOAD_LDS16(Xlb + gx, sXl + ldsoff);
        }
        __syncthreads();

        const int li = lane & 31;
        const int lg = lane >> 5;
#pragma unroll
        for (int ks = 0; ks < 4; ++ks) {
            bf16x8 a_h[2], a_l[2], x_h[2], x_l[2];
#pragma unroll
            for (int m = 0; m < 2; ++m) {
                const int row = wr * 64 + m * 32 + li;
                const int ch  = (ks * 2 + lg) ^ (row & 7);
                const int off = row * 64 + ch * 8;
                a_h[m] = *(const bf16x8*)(sAh + off);
                a_l[m] = *(const bf16x8*)(sAl + off);
            }
#pragma unroll
            for (int n = 0; n < 2; ++n) {
                const int row = wc * 64 + n * 32 + li;
                const int ch  = (ks * 2 + lg) ^ (row & 7);
                const int off = row * 64 + ch * 8;
                x_h[n] = *(const bf16x8*)(sXh + off);
                x_l[n] = *(const bf16x8*)(sXl + off);
            }
#pragma unroll
            for (int m = 0; m < 2; ++m)
#pragma unroll
                for (int n = 0; n < 2; ++n) {
                    acc[m][n] = __builtin_amdgcn_mfma_f32_32x32x16_bf16(a_h[m], x_h[n], acc[m][n], 0, 0, 0);
                    acc[m][n] = __builtin_amdgcn_mfma_f32_32x32x16_bf16(a_h[m], x_l[n], acc[m][n], 0, 0, 0);
                    acc[m][n] = __builtin_amdgcn_mfma_f32_32x32x16_bf16(a_l[m], x_h[n], acc[m][n], 0, 0, 0);
                }
        }
    }

    // epilogue: (acc + b_enc[l]) * stdev + mean
    const int li = lane & 31;
    const int lg = lane >> 5;
    const float be = benc[by >> 1];   // rows of this block span exactly one l
    float sd[2], mn[2];
#pragma unroll
    for (int n = 0; n < 2; ++n) {
        const int col = bx * 128 + wc * 64 + n * 32 + li;
        sd[n] = stdv [b * 256 + col];
        mn[n] = meanv[b * 256 + col];
    }
#pragma unroll
    for (int m = 0; m < 2; ++m)
#pragma unroll
        for (int n = 0; n < 2; ++n) {
            const int col = bx * 128 + wc * 64 + n * 32 + li;
#pragma unroll
            for (int r = 0; r < 16; ++r) {
                const int row = by * 128 + wr * 64 + m * 32 + ((r & 3) + 8 * (r >> 2) + 4 * lg);
                out[((size_t)b * 1024 + row) * 256 + col] = (acc[m][n][r] + be) * sd[n] + mn[n];
            }
        }
}

// ---------------- launch ----------------
extern "C" void kernel_launch(void* const* d_in, const int* in_sizes, int n_in,
                              void* d_out, int out_size, void* d_ws, size_t ws_size,
                              hipStream_t stream) {
    (void)in_sizes; (void)n_in; (void)out_size; (void)ws_size;
    const float* x_enc  = (const float*)d_in[0];
    const float* W_base = (const float*)d_in[4];
    const float* W_enc  = (const float*)d_in[5];
    const float* b_enc  = (const float*)d_in[6];
    float* out = (float*)d_out;

    // workspace layout (needs ~77 MiB)
    char* ws = (char*)d_ws;
    float*    wsP    = (float*)(ws);                 // 11 * 65536 f32 (W^1..W^11)
    float*    wsSum  = (float*)(ws + 0x300000);      // 32*16*256 f32
    float*    wsSq   = (float*)(ws + 0x380000);
    float*    wsMean = (float*)(ws + 0x400000);      // 8192 f32
    float*    wsStd  = (float*)(ws + 0x410000);
    float*    wsRstd = (float*)(ws + 0x420000);
    ushort_t* wsAh   = (ushort_t*)(ws + 0x500000);   // 1024*2048 bf16
    ushort_t* wsAl   = (ushort_t*)(ws + 0x900000);
    ushort_t* wsXh   = (ushort_t*)(ws + 0xD00000);   // 32*256*2048 bf16 (transposed)
    ushort_t* wsXl   = (ushort_t*)(ws + 0x2D00000);

    // W^1 into slot 0
    hipMemcpyAsync(wsP, W_base, 256 * 256 * sizeof(float), hipMemcpyDeviceToDevice, stream);

    stats_partial<<<dim3(16, 32), 256, 0, stream>>>(x_enc, wsSum, wsSq);
    stats_final<<<dim3(32), 256, 0, stream>>>(wsSum, wsSq, wsMean, wsStd, wsRstd);

    // powers: slot m-1 = W^m
    { PowOps o{{0, 0, 0, 0}, {0, 0, 0, 0}, {1, 0, 0, 0}};            // W2
      powmul<<<dim3(1, 64), 256, 0, stream>>>(wsP, o); }
    { PowOps o{{1, 1, 0, 0}, {0, 1, 0, 0}, {2, 3, 0, 0}};            // W3,W4
      powmul<<<dim3(2, 64), 256, 0, stream>>>(wsP, o); }
    { PowOps o{{3, 3, 3, 3}, {0, 1, 2, 3}, {4, 5, 6, 7}};            // W5..W8
      powmul<<<dim3(4, 64), 256, 0, stream>>>(wsP, o); }
    { PowOps o{{7, 7, 7, 0}, {0, 1, 2, 0}, {8, 9, 10, 0}};           // W9..W11
      powmul<<<dim3(3, 64), 256, 0, stream>>>(wsP, o); }

    buildA<<<dim3(8, 1024), 256, 0, stream>>>(wsP, W_enc, wsAh, wsAl);
    normsplit<<<dim3(32, 4, 32), 256, 0, stream>>>(x_enc, wsMean, wsRstd, wsXh, wsXl);

    gemm_kernel<<<dim3(8, 2, 32), 256, 0, stream>>>(wsAh, wsAl, wsXh, wsXl,
                                                    wsMean, wsStd, b_enc, out);
}

// Round 2
// 130.454 us; speedup vs baseline: 1.4382x; 1.4382x over previous
//
#include <hip/hip_runtime.h>
#include <cstdint>
#include <cstddef>

// Problem constants
// B=32, S=2048, P=256, N=256, K=8, L=4, M_out=1024 (=L*P)
// out[b, t, n] = (sum_s A[t,s]*xn[b,s,n] + b_enc[t>>8]) * stdev[b,n] + mean[b,n]
// A[l*256+q, k*256+p] = W_enc[l,k] * (W^(8-k+l))[q,p]
// Single-product bf16 MFMA: added absmax error ~0.005 (analysis in journal),
// baseline pipeline error 0.0156, threshold 0.0869 -> ~4x margin.

typedef unsigned short ushort_t;
typedef unsigned int uint_t;
typedef __attribute__((ext_vector_type(8))) short bf16x8;
typedef __attribute__((ext_vector_type(16))) float f32x16;

__device__ __forceinline__ ushort_t f32_to_bf16(float f) {
    uint_t u = __float_as_uint(f);
    u += 0x7FFFu + ((u >> 16) & 1u);   // RNE (finite values only here)
    return (ushort_t)(u >> 16);
}

// ---------------- stats: mean/std per (b,n) over s=0..2047 ----------------
__global__ void stats_partial(const float* __restrict__ x,
                              float* __restrict__ psum, float* __restrict__ psq) {
    const int c = blockIdx.x;   // chunk 0..15 (128 s each)
    const int b = blockIdx.y;   // 0..31
    const int n = threadIdx.x;  // 0..255
    float s = 0.f, q = 0.f;
    const float* xp = x + ((size_t)b * 2048 + (size_t)c * 128) * 256 + n;
#pragma unroll 4
    for (int i = 0; i < 128; ++i) { float v = xp[(size_t)i * 256]; s += v; q += v * v; }
    psum[(b * 16 + c) * 256 + n] = s;
    psq [(b * 16 + c) * 256 + n] = q;
}

__global__ void stats_final(const float* __restrict__ psum, const float* __restrict__ psq,
                            float* __restrict__ meanv, float* __restrict__ stdv,
                            float* __restrict__ rstdv) {
    const int b = blockIdx.x; const int n = threadIdx.x;
    float s = 0.f, q = 0.f;
#pragma unroll
    for (int c = 0; c < 16; ++c) { s += psum[(b * 16 + c) * 256 + n]; q += psq[(b * 16 + c) * 256 + n]; }
    const float mean = s * (1.0f / 2048.0f);
    float var = q * (1.0f / 2048.0f) - mean * mean;
    var = fmaxf(var, 0.0f);
    const float sd = sqrtf(var + 1e-5f);
    meanv[b * 256 + n] = mean;
    stdv [b * 256 + n] = sd;
    rstdv[b * 256 + n] = 1.0f / sd;
}

// ---------------- W powers: C = A * B for up to 4 (slot) triples ----------------
struct PowOps { int sa[4]; int sb[4]; int sd[4]; };

__global__ void powmul(float* __restrict__ Pw, PowOps ops) {
    __shared__ float As[4 * 256];
    const int mat = blockIdx.x;
    const int r0  = blockIdx.y * 4;      // 64 row-blocks of 4
    const int tid = threadIdx.x;         // 256
    const float* A  = Pw + (size_t)ops.sa[mat] * 65536;
    const float* Bm = Pw + (size_t)ops.sb[mat] * 65536;
    float* C        = Pw + (size_t)ops.sd[mat] * 65536;
#pragma unroll
    for (int i = 0; i < 4; ++i) As[i * 256 + tid] = A[(r0 + i) * 256 + tid];
    __syncthreads();
    float a0 = 0.f, a1 = 0.f, a2 = 0.f, a3 = 0.f;
    for (int p = 0; p < 256; p += 8) {
        float bv[8];
#pragma unroll
        for (int u = 0; u < 8; ++u) bv[u] = Bm[(p + u) * 256 + tid];
#pragma unroll
        for (int u = 0; u < 8; ++u) {
            a0 += As[0 * 256 + p + u] * bv[u];
            a1 += As[1 * 256 + p + u] * bv[u];
            a2 += As[2 * 256 + p + u] * bv[u];
            a3 += As[3 * 256 + p + u] * bv[u];
        }
    }
    C[(r0 + 0) * 256 + tid] = a0;
    C[(r0 + 1) * 256 + tid] = a1;
    C[(r0 + 2) * 256 + tid] = a2;
    C[(r0 + 3) * 256 + tid] = a3;
}

// ---------------- build A (scaled by W_enc), bf16 ----------------
__global__ void buildA(const float* __restrict__ Pw, const float* __restrict__ Wenc,
                       ushort_t* __restrict__ Ah) {
    const int t = blockIdx.y;                      // 0..1023
    const int s = blockIdx.x * 256 + threadIdx.x;  // 0..2047
    const int l = t >> 8, q = t & 255, k = s >> 8, p = s & 255;
    const int m = 8 - k + l;                       // 1..11
    const float val = Wenc[l * 8 + k] * Pw[(size_t)(m - 1) * 65536 + q * 256 + p];
    Ah[(size_t)t * 2048 + s] = f32_to_bf16(val);
}

// ---------------- normalize + transpose: Xt[b][n][s] bf16 ----------------
__global__ void normsplit(const float* __restrict__ x, const float* __restrict__ meanv,
                          const float* __restrict__ rstdv, ushort_t* __restrict__ Xh) {
    __shared__ float lds[64 * 65];                 // [s-within-tile][n-within-tile], padded
    const int st = blockIdx.x;                     // s-tile 0..31
    const int nt = blockIdx.y;                     // n-tile 0..3
    const int b  = blockIdx.z;                     // 0..31
    const int tid = threadIdx.x;
    const int j = tid & 63;
    const int n = nt * 64 + j;
    const float mn = meanv[b * 256 + n];
    const float rs = rstdv[b * 256 + n];
    const int s0 = st * 64;
#pragma unroll
    for (int it = 0; it < 16; ++it) {
        const int ii = (tid >> 6) + it * 4;
        const float v = x[((size_t)b * 2048 + s0 + ii) * 256 + n];
        lds[ii * 65 + j] = (v - mn) * rs;
    }
    __syncthreads();
#pragma unroll
    for (int step = 0; step < 8; ++step) {
        const int npr = step * 8 + (tid >> 5);     // 0..63 (n within tile)
        const int sp  = (tid & 31) * 2;            // even s within tile
        const float f0 = lds[sp * 65 + npr];
        const float f1 = lds[(sp + 1) * 65 + npr];
        const uint_t packed = (uint_t)f32_to_bf16(f0) | ((uint_t)f32_to_bf16(f1) << 16);
        *(uint_t*)(Xh + ((size_t)b * 256 + nt * 64 + npr) * 2048 + s0 + sp) = packed;
    }
}

// ---------------- GEMM: out[b,t,n] = (A @ Xt[b]^T)[t,n] epilogue-fused ----------------
// A: [1024][2048] bf16 row-major. Xt: [b][256][2048] bf16.
// Tile 128x128, BK=64, 4 waves (2x2), 32x32x16 bf16 MFMA, single product.
#define GLOAD_LDS16(gsrc, ldst) \
    __builtin_amdgcn_global_load_lds((const __attribute__((address_space(1))) void*)(gsrc), \
                                     (__attribute__((address_space(3))) void*)(ldst), 16, 0, 0)

__global__ __launch_bounds__(256, 2) void gemm_kernel(
    const ushort_t* __restrict__ Ah, const ushort_t* __restrict__ Xh,
    const float* __restrict__ meanv, const float* __restrict__ stdv,
    const float* __restrict__ benc, float* __restrict__ out)
{
    __shared__ ushort_t sA[128 * 64];
    __shared__ ushort_t sX[128 * 64];

    // X-locality swizzle: all 8 blocks sharing an X slice (same bx,b) land on
    // one XCD (xcd = (bx+2b)&7), in consecutive dispatch order -> X slice is
    // L2-hot for its 7 reusers; A refills come from L3.
    const int flat = blockIdx.x + (blockIdx.y << 3) + (blockIdx.z << 4); // 0..511
    const int xcd = flat & 7;
    const int r2  = flat >> 3;          // 0..63
    const int by  = r2 & 7;             // M tile: rows by*128
    const int g   = xcd + ((r2 >> 3) << 3); // 0..63
    const int bx  = g & 1;              // N tile: cols bx*128
    const int b   = g >> 1;             // batch

    const int tid  = threadIdx.x;
    const int lane = tid & 63;
    const int w    = tid >> 6;     // wave 0..3
    const int wr   = w >> 1, wc = w & 1;

    const ushort_t* Xb = Xh + (size_t)b * (256 * 2048);

    const int srow   = lane >> 3;  // 0..7 row-within-8 for staging
    const int schunk = lane & 7;   // 16B chunk within 128B row

    f32x16 acc[2][2];
#pragma unroll
    for (int m = 0; m < 2; ++m)
#pragma unroll
        for (int n = 0; n < 2; ++n)
#pragma unroll
            for (int rr = 0; rr < 16; ++rr) acc[m][n][rr] = 0.0f;

    for (int kt = 0; kt < 32; ++kt) {
        const int k0 = kt * 64;
        __syncthreads();
#pragma unroll
        for (int i = 0; i < 4; ++i) {
            const int r  = i * 32 + w * 8 + srow;          // LDS row 0..127
            const int ch = schunk ^ (r & 7);               // pre-swizzled source chunk
            const size_t ga = (size_t)(by * 128 + r) * 2048 + k0 + ch * 8;
            const size_t gx = (size_t)(bx * 128 + r) * 2048 + k0 + ch * 8;
            const uint_t ldsoff = (uint_t)(i * 32 + w * 8) * 64;  // elements
            GLOAD_LDS16(Ah + ga, sA + ldsoff);
            GLOAD_LDS16(Xb + gx, sX + ldsoff);
        }
        __syncthreads();

        const int li = lane & 31;
        const int lg = lane >> 5;
#pragma unroll
        for (int ks = 0; ks < 4; ++ks) {
            bf16x8 a_h[2], x_h[2];
#pragma unroll
            for (int m = 0; m < 2; ++m) {
                const int row = wr * 64 + m * 32 + li;
                const int ch  = (ks * 2 + lg) ^ (row & 7);
                a_h[m] = *(const bf16x8*)(sA + row * 64 + ch * 8);
            }
#pragma unroll
            for (int n = 0; n < 2; ++n) {
                const int row = wc * 64 + n * 32 + li;
                const int ch  = (ks * 2 + lg) ^ (row & 7);
                x_h[n] = *(const bf16x8*)(sX + row * 64 + ch * 8);
            }
#pragma unroll
            for (int m = 0; m < 2; ++m)
#pragma unroll
                for (int n = 0; n < 2; ++n)
                    acc[m][n] = __builtin_amdgcn_mfma_f32_32x32x16_bf16(a_h[m], x_h[n], acc[m][n], 0, 0, 0);
        }
    }

    // epilogue: (acc + b_enc[l]) * stdev + mean
    const int li = lane & 31;
    const int lg = lane >> 5;
    const float be = benc[by >> 1];   // rows of this block span exactly one l
    float sd[2], mn[2];
#pragma unroll
    for (int n = 0; n < 2; ++n) {
        const int col = bx * 128 + wc * 64 + n * 32 + li;
        sd[n] = stdv [b * 256 + col];
        mn[n] = meanv[b * 256 + col];
    }
#pragma unroll
    for (int m = 0; m < 2; ++m)
#pragma unroll
        for (int n = 0; n < 2; ++n) {
            const int col = bx * 128 + wc * 64 + n * 32 + li;
#pragma unroll
            for (int rr = 0; rr < 16; ++rr) {
                const int row = by * 128 + wr * 64 + m * 32 + ((rr & 3) + 8 * (rr >> 2) + 4 * lg);
                out[((size_t)b * 1024 + row) * 256 + col] = (acc[m][n][rr] + be) * sd[n] + mn[n];
            }
        }
}

// ---------------- launch ----------------
extern "C" void kernel_launch(void* const* d_in, const int* in_sizes, int n_in,
                              void* d_out, int out_size, void* d_ws, size_t ws_size,
                              hipStream_t stream) {
    (void)in_sizes; (void)n_in; (void)out_size; (void)ws_size;
    const float* x_enc  = (const float*)d_in[0];
    const float* W_base = (const float*)d_in[4];
    const float* W_enc  = (const float*)d_in[5];
    const float* b_enc  = (const float*)d_in[6];
    float* out = (float*)d_out;

    // workspace layout (~45 MiB used)
    char* ws = (char*)d_ws;
    float*    wsP    = (float*)(ws);                 // 11 * 65536 f32 (W^1..W^11)
    float*    wsSum  = (float*)(ws + 0x300000);      // 32*16*256 f32
    float*    wsSq   = (float*)(ws + 0x380000);
    float*    wsMean = (float*)(ws + 0x400000);      // 8192 f32
    float*    wsStd  = (float*)(ws + 0x410000);
    float*    wsRstd = (float*)(ws + 0x420000);
    ushort_t* wsAh   = (ushort_t*)(ws + 0x500000);   // 1024*2048 bf16
    ushort_t* wsXh   = (ushort_t*)(ws + 0x900000);   // 32*256*2048 bf16 (transposed)

    // W^1 into slot 0
    hipMemcpyAsync(wsP, W_base, 256 * 256 * sizeof(float), hipMemcpyDeviceToDevice, stream);

    stats_partial<<<dim3(16, 32), 256, 0, stream>>>(x_enc, wsSum, wsSq);
    stats_final<<<dim3(32), 256, 0, stream>>>(wsSum, wsSq, wsMean, wsStd, wsRstd);

    // powers: slot m-1 = W^m
    { PowOps o{{0, 0, 0, 0}, {0, 0, 0, 0}, {1, 0, 0, 0}};            // W2
      powmul<<<dim3(1, 64), 256, 0, stream>>>(wsP, o); }
    { PowOps o{{1, 1, 0, 0}, {0, 1, 0, 0}, {2, 3, 0, 0}};            // W3,W4
      powmul<<<dim3(2, 64), 256, 0, stream>>>(wsP, o); }
    { PowOps o{{3, 3, 3, 3}, {0, 1, 2, 3}, {4, 5, 6, 7}};            // W5..W8
      powmul<<<dim3(4, 64), 256, 0, stream>>>(wsP, o); }
    { PowOps o{{7, 7, 7, 0}, {0, 1, 2, 0}, {8, 9, 10, 0}};           // W9..W11
      powmul<<<dim3(3, 64), 256, 0, stream>>>(wsP, o); }

    buildA<<<dim3(8, 1024), 256, 0, stream>>>(wsP, W_enc, wsAh);
    normsplit<<<dim3(32, 4, 32), 256, 0, stream>>>(x_enc, wsMean, wsRstd, wsXh);

    gemm_kernel<<<dim3(8, 2, 32), 256, 0, stream>>>(wsAh, wsXh, wsMean, wsStd, b_enc, out);
}